// Round 9
// baseline (260.751 us; speedup 1.0000x reference)
//
#include <hip/hip_runtime.h>

#define B_  4
#define N_  2048
#define H_  16
#define HD_ 1024

typedef short  bf16x8 __attribute__((ext_vector_type(8)));
typedef short  bf16x4 __attribute__((ext_vector_type(4)));
typedef float  f32x4  __attribute__((ext_vector_type(4)));

// round-half-up bf16: max error 0.5 ulp (same bound as RNE; only ties differ).
// Harness-proven (rounds 4-8 absmax 9.155e-5, identical to RNE build).
static __device__ __forceinline__ unsigned short f2bf(float f) {
    unsigned int u = __builtin_bit_cast(unsigned int, f);
    return (unsigned short)((u + 0x8000u) >> 16);
}
// pack two floats -> (bf16(hi)<<16)|bf16(lo), 3 VALU ops (RHU rounding)
static __device__ __forceinline__ unsigned f2bf2pack(float lo, float hi) {
    unsigned a = __builtin_bit_cast(unsigned, lo) + 0x8000u;
    unsigned b = __builtin_bit_cast(unsigned, hi) + 0x8000u;
    return __builtin_amdgcn_perm(b, a, 0x07060302u);
}

// ---------------- precompute: W f32->bf16 (q-scale folded) + mask->float bias ----------------
// grid 4 blocks x 256 threads. wbf[p][64][64] bf16; mb[b][n] = mask ? 0 : -1e30.
__global__ __launch_bounds__(256) void wconv_kernel(
    const float* __restrict__ WQ, const float* __restrict__ WK,
    const float* __restrict__ WV, const int* __restrict__ maskp,
    unsigned short* __restrict__ wbf, float* __restrict__ mb)
{
    const int p = blockIdx.x;
    const int t = threadIdx.x;
    if (p == 3) {
        #pragma unroll
        for (int i = 0; i < 32; ++i) {
            int idx = i * 256 + t;          // B_*N_ = 8192
            mb[idx] = maskp[idx] ? 0.f : -1e30f;
        }
        return;
    }
    const float* W = (p == 0) ? WQ : (p == 1) ? WK : WV;
    const float scl = (p == 0) ? 0.180336880f : 1.f;   // 0.125 * log2(e) folded into W_Q
    const float* src = W + t * 16;
    unsigned short* dst = wbf + p * 4096 + t * 16;
    float4 f[4];
    #pragma unroll
    for (int i = 0; i < 4; ++i) f[i] = *reinterpret_cast<const float4*>(src + i * 4);
    uint4 o0, o1;
    o0.x = f2bf2pack(f[0].x * scl, f[0].y * scl);
    o0.y = f2bf2pack(f[0].z * scl, f[0].w * scl);
    o0.z = f2bf2pack(f[1].x * scl, f[1].y * scl);
    o0.w = f2bf2pack(f[1].z * scl, f[1].w * scl);
    o1.x = f2bf2pack(f[2].x * scl, f[2].y * scl);
    o1.y = f2bf2pack(f[2].z * scl, f[2].w * scl);
    o1.z = f2bf2pack(f[3].x * scl, f[3].y * scl);
    o1.w = f2bf2pack(f[3].z * scl, f[3].w * scl);
    *reinterpret_cast<uint4*>(dst)     = o0;
    *reinterpret_cast<uint4*>(dst + 8) = o1;
}

// ---------------- projection: register-direct; v written in MFMA-fragment-linear layout ----------------
// grid (N/64, H, B*3); z = b*3 + p. q,k out: [b,h,n,64] row-major (LDS transpose).
// v out: fragment-linear [bh][kvt][ct][kh][l15][quad][jhi][jo] so attn reads each
// av[ct][kh] as ONE coalesced 16B load (wave covers exactly 1KB contiguous).
// p==2 path: direct register->global stores, NO LDS, NO barrier.
__global__ __launch_bounds__(256) void proj_kernel(
    const float* __restrict__ Qv, const float* __restrict__ Kv,
    const float* __restrict__ Vv, const unsigned short* __restrict__ wbf,
    unsigned short* __restrict__ qs, unsigned short* __restrict__ ks,
    unsigned short* __restrict__ vt)
{
    __shared__ __align__(16) unsigned short sb[64][72];

    const int tid  = threadIdx.x;
    const int wq   = tid >> 6;
    const int lane = tid & 63;
    const int l15  = lane & 15;
    const int quad = lane >> 4;

    const int i0 = blockIdx.x * 64;
    const int h  = blockIdx.y;
    const int bz = blockIdx.z;
    const int b  = bz / 3;
    const int p  = bz - b * 3;

    const size_t bh = (size_t)b * H_ + h;
    const float* inp = ((p == 0) ? Qv : (p == 1) ? Kv : Vv)
                       + ((size_t)b * N_ + i0) * HD_ + h * 64;

    // W B-fragments: row t*16+l15 (out-dim), cols kh*32+quad*8, pre-converted bf16
    const unsigned short* wb = wbf + p * 4096;
    bf16x8 bw[4][2];
    #pragma unroll
    for (int t = 0; t < 4; ++t)
        #pragma unroll
        for (int kh = 0; kh < 2; ++kh)
            bw[t][kh] = *reinterpret_cast<const bf16x8*>(wb + (t * 16 + l15) * 64 + kh * 32 + quad * 8);

    // x A-fragments: token wq*16+l15, f32 -> bf16 in regs
    const float* xp = inp + (size_t)(wq * 16 + l15) * HD_;
    bf16x8 ax[2];
    #pragma unroll
    for (int kh = 0; kh < 2; ++kh) {
        float4 f0 = *reinterpret_cast<const float4*>(xp + kh * 32 + quad * 8);
        float4 f1 = *reinterpret_cast<const float4*>(xp + kh * 32 + quad * 8 + 4);
        uint4 u = uint4{f2bf2pack(f0.x, f0.y), f2bf2pack(f0.z, f0.w),
                        f2bf2pack(f1.x, f1.y), f2bf2pack(f1.z, f1.w)};
        ax[kh] = __builtin_bit_cast(bf16x8, u);
    }

    f32x4 C[4];   // C[t][r] = y[token = wq*16 + quad*4 + r][outdim = t*16 + l15]
    #pragma unroll
    for (int t = 0; t < 4; ++t) {
        C[t] = f32x4{0.f, 0.f, 0.f, 0.f};
        #pragma unroll
        for (int kh = 0; kh < 2; ++kh)
            C[t] = __builtin_amdgcn_mfma_f32_16x16x32_bf16(ax[kh], bw[t][kh], C[t], 0, 0, 0);
    }

    if (p < 2) {
        // q,k: [bh, n, 64] via LDS transpose (scale already folded into W_Q)
        #pragma unroll
        for (int t = 0; t < 4; ++t)
            #pragma unroll
            for (int r = 0; r < 4; ++r)
                sb[wq * 16 + quad * 4 + r][t * 16 + l15] = f2bf(C[t][r]);
        __syncthreads();
        unsigned short* dst = ((p == 0) ? qs : ks) + ((size_t)bh * N_ + i0) * 64;
        #pragma unroll
        for (int v = 0; v < 2; ++v) {
            int idx = tid + v * 256;
            int row = idx >> 3, c0 = (idx & 7) * 8;
            *reinterpret_cast<uint4*>(dst + (size_t)row * 64 + c0) =
                *reinterpret_cast<const uint4*>(&sb[row][c0]);
        }
    } else {
        // v fragment-linear: token tk = wq*16+quad*4+r -> kh=wq>>1, jhi=wq&1, q=quad, jo=r
        // elem offset = kvt*4096 + ((t*2 + (wq>>1))*16 + l15)*32 + quad*8 + (wq&1)*4 + r
        unsigned short* vf = vt + (size_t)bh * 64 * N_ + (size_t)blockIdx.x * 4096;
        #pragma unroll
        for (int t = 0; t < 4; ++t) {
            uint2 u;
            u.x = f2bf2pack(C[t][0], C[t][1]);
            u.y = f2bf2pack(C[t][2], C[t][3]);
            *reinterpret_cast<uint2*>(vf + ((t * 2 + (wq >> 1)) * 16 + l15) * 32
                                         + quad * 8 + (wq & 1) * 4) = u;
        }
    }
}

// ---------------- transposed flash attention: ZERO LDS, ZERO barriers ----------------
// S^T = K Q^T, O^T = V^T P^T. P never touches LDS: the S^T C-layout registers
// ARE the P B-fragment under the k-permutation sigma(k). S acc initialized with
// the k-mask bias (mb depends only on column j = C-layout index of S^T).
// K/V/mask-bias fragments load DIRECTLY from global (L1/L2-hot: 512KB per bh,
// shared by 8 co-located blocks). No barriers -> no lockstep stalls; compiler
// free to pipeline loads across kv-tiles. XCD swizzle: 512 wg = 8 XCDs x 64;
// each XCD owns 8 whole bh panels (R6-proven: FETCH 139->25MB).
// grid (N/256, B*H), block 256 = 4 waves, each wave owns 64 q-rows.
__global__ __launch_bounds__(256) void attn_kernel(
    const unsigned short* __restrict__ qs, const unsigned short* __restrict__ ks,
    const unsigned short* __restrict__ vt, const int* __restrict__ maskp,
    const float* __restrict__ mb, float* __restrict__ out)
{
    const int tid  = threadIdx.x;
    const int w    = tid >> 6;
    const int lane = tid & 63;
    const int l15  = lane & 15;
    const int quad = lane >> 4;

    // bijective XCD swizzle: lin = hi*64 + xblk*8 + xcd; bh = xcd*8 + hi
    const int lin  = blockIdx.y * gridDim.x + blockIdx.x;   // 0..511
    const int xcd  = lin & 7;
    const int bh   = xcd * 8 + (lin >> 6);
    const int xblk = (lin >> 3) & 7;

    const int i0 = xblk * 256;
    const int b  = bh >> 4;
    const int h  = bh & 15;
    const int qrow0 = i0 + w * 64;

    // Q fragments (B-operand) for 4 row-tiles, straight from global
    bf16x8 aq[4][2];
    float  qm[4];
    #pragma unroll
    for (int rt = 0; rt < 4; ++rt) {
        const unsigned short* qrow = qs + ((size_t)bh * N_ + qrow0 + rt * 16 + l15) * 64;
        aq[rt][0] = *reinterpret_cast<const bf16x8*>(qrow + quad * 8);
        aq[rt][1] = *reinterpret_cast<const bf16x8*>(qrow + 32 + quad * 8);
        qm[rt] = maskp[b * N_ + qrow0 + rt * 16 + l15] ? 1.f : 0.f;
    }

    bf16x8 aones;
    #pragma unroll
    for (int j = 0; j < 8; ++j) aones[j] = (short)0x3F80;

    f32x4 O[4][4];     // [rt][ct2] : O^T[d-block ct2][qrow-block rt]
    f32x4 L[4];
    #pragma unroll
    for (int rt = 0; rt < 4; ++rt) {
        L[rt] = f32x4{0.f, 0.f, 0.f, 0.f};
        #pragma unroll
        for (int c = 0; c < 4; ++c) O[rt][c] = f32x4{0.f, 0.f, 0.f, 0.f};
    }

    const unsigned short* kbase = ks + (size_t)bh * N_ * 64;
    const unsigned short* vfb   = vt + (size_t)bh * 64 * N_;
    const float* mbase = mb + b * N_;

    for (int kv0 = 0; kv0 < N_; kv0 += 64) {
        // K A-fragments direct from row-major ks (L1-reused across the 4 waves)
        bf16x8 ak[4][2];
        #pragma unroll
        for (int ct = 0; ct < 4; ++ct)
            #pragma unroll
            for (int kh = 0; kh < 2; ++kh)
                ak[ct][kh] = *reinterpret_cast<const bf16x8*>(
                    kbase + (size_t)(kv0 + ct * 16 + l15) * 64 + kh * 32 + quad * 8);

        // V A-fragments direct from fragment-linear vt: one 16B load each
        const unsigned short* vf = vfb + (size_t)(kv0 >> 6) * 4096;
        bf16x8 av[4][2];
        #pragma unroll
        for (int ct = 0; ct < 4; ++ct)
            #pragma unroll
            for (int kh = 0; kh < 2; ++kh)
                av[ct][kh] = *reinterpret_cast<const bf16x8*>(
                    vf + ((ct * 2 + kh) * 16 + l15) * 32 + quad * 8);

        // k-mask bias: one f32x4 load per ct from precomputed mb
        f32x4 kbv[4];
        #pragma unroll
        for (int ct = 0; ct < 4; ++ct)
            kbv[ct] = *reinterpret_cast<const f32x4*>(mbase + kv0 + ct * 16 + quad * 4);

        #pragma unroll
        for (int rt = 0; rt < 4; ++rt) {
            // S^T: lane holds S[qrow=rt*16+l15][j=16ct+4q+r]; acc starts at mb[j]
            f32x4 S[4];
            #pragma unroll
            for (int ct = 0; ct < 4; ++ct) {
                S[ct] = kbv[ct];
                #pragma unroll
                for (int kh = 0; kh < 2; ++kh)
                    S[ct] = __builtin_amdgcn_mfma_f32_16x16x32_bf16(ak[ct][kh], aq[rt][kh], S[ct], 0, 0, 0);
            }
            // masked exp2 (q pre-scaled by log2e via W_Q); pack into P B-fragments
            unsigned pk[4][2];
            #pragma unroll
            for (int ct = 0; ct < 4; ++ct) {
                float e0 = __builtin_amdgcn_exp2f(S[ct][0] * qm[rt]);
                float e1 = __builtin_amdgcn_exp2f(S[ct][1] * qm[rt]);
                float e2 = __builtin_amdgcn_exp2f(S[ct][2] * qm[rt]);
                float e3 = __builtin_amdgcn_exp2f(S[ct][3] * qm[rt]);
                pk[ct][0] = f2bf2pack(e0, e1);
                pk[ct][1] = f2bf2pack(e2, e3);
            }
            bf16x8 ap[2];
            #pragma unroll
            for (int kh = 0; kh < 2; ++kh) {
                uint4 u = uint4{pk[2 * kh][0], pk[2 * kh][1], pk[2 * kh + 1][0], pk[2 * kh + 1][1]};
                ap[kh] = __builtin_bit_cast(bf16x8, u);
            }
            // row-sums: D[m][n=qrow] = sum_k P — every lane gets its own qrow's L
            #pragma unroll
            for (int kh = 0; kh < 2; ++kh)
                L[rt] = __builtin_amdgcn_mfma_f32_16x16x32_bf16(aones, ap[kh], L[rt], 0, 0, 0);
            // O^T += V^T P^T
            #pragma unroll
            for (int ct = 0; ct < 4; ++ct)
                #pragma unroll
                for (int kh = 0; kh < 2; ++kh)
                    O[rt][ct] = __builtin_amdgcn_mfma_f32_16x16x32_bf16(av[ct][kh], ap[kh], O[rt][ct], 0, 0, 0);
        }
    }

    // epilogue: lane (q,l15) holds O^T[d=16ct+4q+r][qrow=rt*16+l15]; L[rt] components all equal
    #pragma unroll
    for (int rt = 0; rt < 4; ++rt) {
        float inv = 1.f / L[rt][0];
        float* orow = out + ((size_t)b * N_ + qrow0 + rt * 16 + l15) * HD_ + h * 64 + quad * 4;
        #pragma unroll
        for (int ct = 0; ct < 4; ++ct)
            #pragma unroll
            for (int r = 0; r < 4; ++r)
                orow[ct * 16 + r] = O[rt][ct][r] * inv;
    }
}

extern "C" void kernel_launch(void* const* d_in, const int* in_sizes, int n_in,
                              void* d_out, int out_size, void* d_ws, size_t ws_size,
                              hipStream_t stream)
{
    const float* Qv  = (const float*)d_in[0];
    const float* Kv  = (const float*)d_in[1];
    const float* Vv  = (const float*)d_in[2];
    const float* WQ  = (const float*)d_in[3];
    const float* WK  = (const float*)d_in[4];
    const float* WV  = (const float*)d_in[5];
    const int*   msk = (const int*)d_in[6];
    float* out = (float*)d_out;

    const size_t per = (size_t)B_ * H_ * N_ * 64;   // 8.4M elems, bf16
    unsigned short* qsb = (unsigned short*)d_ws;
    unsigned short* ksb = qsb + per;
    unsigned short* vtb = ksb + per;
    unsigned short* wbf = vtb + per;                // 3 * 4096 bf16 = 24KB
    float*          mbf = (float*)(wbf + 3 * 4096); // B*N floats = 32KB

    wconv_kernel<<<dim3(4), 256, 0, stream>>>(WQ, WK, WV, msk, wbf, mbf);
    proj_kernel<<<dim3(N_ / 64, H_, B_ * 3), 256, 0, stream>>>(Qv, Kv, Vv, wbf, qsb, ksb, vtb);
    attn_kernel<<<dim3(N_ / 256, B_ * H_), 256, 0, stream>>>(qsb, ksb, vtb, msk, mbf, out);
}

// Round 10
// 227.920 us; speedup vs baseline: 1.1440x; 1.1440x over previous
//
#include <hip/hip_runtime.h>

#define B_  4
#define N_  2048
#define H_  16
#define HD_ 1024

typedef short  bf16x8 __attribute__((ext_vector_type(8)));
typedef short  bf16x4 __attribute__((ext_vector_type(4)));
typedef float  f32x4  __attribute__((ext_vector_type(4)));

// round-half-up bf16: max error 0.5 ulp (same bound as RNE; only ties differ).
// Harness-proven (rounds 4-9 absmax 9.155e-5, identical to RNE build).
static __device__ __forceinline__ unsigned short f2bf(float f) {
    unsigned int u = __builtin_bit_cast(unsigned int, f);
    return (unsigned short)((u + 0x8000u) >> 16);
}
// pack two floats -> (bf16(hi)<<16)|bf16(lo), 3 VALU ops (RHU rounding)
static __device__ __forceinline__ unsigned f2bf2pack(float lo, float hi) {
    unsigned a = __builtin_bit_cast(unsigned, lo) + 0x8000u;
    unsigned b = __builtin_bit_cast(unsigned, hi) + 0x8000u;
    return __builtin_amdgcn_perm(b, a, 0x07060302u);
}

// ---------------- projection via MFMA (R3-proven staging) ----------------
// grid (N/64, H, B*3); z = b*3 + p
// q,k out: [b,h,n,64] bf16 (q pre-scaled by 0.125*log2e), via LDS transpose.
// v out: FRAGMENT-LINEAR [bh][kvt][ct*2+kh][l15][quad*8+jhi*4+jo] (R9-proven
// mapping) written DIRECTLY from C registers — no LDS, no extra barriers.
__global__ __launch_bounds__(256) void proj_kernel(
    const float* __restrict__ Qv, const float* __restrict__ Kv,
    const float* __restrict__ Vv, const float* __restrict__ WQ,
    const float* __restrict__ WK, const float* __restrict__ WV,
    unsigned short* __restrict__ qs, unsigned short* __restrict__ ks,
    unsigned short* __restrict__ vt)
{
    __shared__ __align__(16) unsigned short xb[64][72];
    __shared__ __align__(16) unsigned short Wb[64][72];
    unsigned short (*sb)[72] = xb;   // overlay: written only after all xb reads

    const int tid  = threadIdx.x;
    const int wq   = tid >> 6;
    const int lane = tid & 63;
    const int l15  = lane & 15;
    const int quad = lane >> 4;

    const int i0 = blockIdx.x * 64;
    const int h  = blockIdx.y;
    const int bz = blockIdx.z;
    const int b  = bz / 3;
    const int p  = bz - b * 3;

    const size_t inbase = ((size_t)b * N_ + i0) * HD_ + h * 64;
    const size_t bh     = (size_t)b * H_ + h;

    const float* W   = (p == 0) ? WQ : (p == 1) ? WK : WV;
    const float* inp = ((p == 0) ? Qv : (p == 1) ? Kv : Vv) + inbase;

    for (int v = tid; v < 1024; v += 256) {
        int tok = v >> 4, c4 = (v & 15) * 4;
        float4 f = *reinterpret_cast<const float4*>(inp + (size_t)tok * HD_ + c4);
        uint2 u;
        u.x = f2bf2pack(f.x, f.y);
        u.y = f2bf2pack(f.z, f.w);
        *reinterpret_cast<uint2*>(&xb[tok][c4]) = u;
        float4 g = *reinterpret_cast<const float4*>(W + (size_t)v * 4);
        uint2 w2;
        w2.x = f2bf2pack(g.x, g.y);
        w2.y = f2bf2pack(g.z, g.w);
        *reinterpret_cast<uint2*>(&Wb[tok][c4]) = w2;
    }
    __syncthreads();

    bf16x8 ax[2];
    #pragma unroll
    for (int kh = 0; kh < 2; ++kh)
        ax[kh] = *reinterpret_cast<const bf16x8*>(&xb[wq * 16 + l15][kh * 32 + quad * 8]);

    f32x4 C[4];
    #pragma unroll
    for (int t = 0; t < 4; ++t) {
        C[t] = f32x4{0.f, 0.f, 0.f, 0.f};
        #pragma unroll
        for (int kh = 0; kh < 2; ++kh) {
            bf16x8 bw = *reinterpret_cast<const bf16x8*>(&Wb[t * 16 + l15][kh * 32 + quad * 8]);
            C[t] = __builtin_amdgcn_mfma_f32_16x16x32_bf16(ax[kh], bw, C[t], 0, 0, 0);
        }
    }

    if (p < 2) {
        __syncthreads();   // all xb reads complete before sb(=xb) is overwritten
        const float scl = (p == 0) ? 0.180336880f : 1.f;  // 0.125 * log2(e)
        #pragma unroll
        for (int t = 0; t < 4; ++t)
            #pragma unroll
            for (int r = 0; r < 4; ++r)
                sb[wq * 16 + quad * 4 + r][t * 16 + l15] = f2bf(C[t][r] * scl);
        __syncthreads();
        unsigned short* dst = ((p == 0) ? qs : ks) + ((size_t)bh * N_ + i0) * 64;
        for (int v = tid; v < 512; v += 256) {
            int row = v >> 3, c0 = (v & 7) * 8;
            *reinterpret_cast<uint4*>(dst + (size_t)row * 64 + c0) =
                *reinterpret_cast<const uint4*>(&sb[row][c0]);
        }
    } else {
        // v fragment-linear: token tk = wq*16+quad*4+r -> kh=wq>>1, jhi=wq&1
        // elem offset = kvt*4096 + ((t*2 + (wq>>1))*16 + l15)*32 + quad*8 + (wq&1)*4 + r
        unsigned short* vf = vt + (size_t)bh * 64 * N_ + (size_t)blockIdx.x * 4096;
        #pragma unroll
        for (int t = 0; t < 4; ++t) {
            uint2 u;
            u.x = f2bf2pack(C[t][0], C[t][1]);
            u.y = f2bf2pack(C[t][2], C[t][3]);
            *reinterpret_cast<uint2*>(vf + ((t * 2 + (wq >> 1)) * 16 + l15) * 32
                                         + quad * 8 + (wq & 1) * 4) = u;
        }
    }
}

// ---------------- transposed flash attention: staged K, direct V, XCD swizzle ----------------
// S^T = K Q^T, O^T = V^T P^T. P never touches LDS: the S^T C-layout registers
// ARE the P B-fragment under the k-permutation sigma(k). S acc initialized with
// the k-mask bias (kb depends only on column j = C-layout index of S^T).
// K + kb staged in LDS (shared by all 4 waves; R9 proved direct-K is slower).
// V read DIRECTLY from fragment-linear vt: 8 global_load_dwordx4 per tile with
// immediate offsets, XCD-L2-hot (R9-proven layout) — removes V staging + the
// 16 b64 reads + 16 recombine ops per tile. LDS 18.4 -> 9.5 KB.
// XCD swizzle (R9-proven): 512 wg = 8 XCDs x 64; each XCD owns 8 bh panels.
// grid (N/256, B*H), block 256 = 4 waves; launch_bounds(256,2) proven safe.
__global__ __launch_bounds__(256, 2) void attn_kernel(
    const unsigned short* __restrict__ qs, const unsigned short* __restrict__ ks,
    const unsigned short* __restrict__ vt, const int* __restrict__ maskp,
    float* __restrict__ out)
{
    __shared__ __align__(16) unsigned short Ks[64][72];   // stride 36 dw: b128 reads 2-way (free)
    __shared__ float kb[64];

    const int tid  = threadIdx.x;
    const int w    = tid >> 6;
    const int lane = tid & 63;
    const int l15  = lane & 15;
    const int quad = lane >> 4;

    // bijective XCD swizzle: gridDim.x=8 -> xcd = lin&7; bh = xcd*8 + lin>>6
    const int lin  = blockIdx.y * gridDim.x + blockIdx.x;   // 0..511
    const int xcd  = lin & 7;
    const int bh   = xcd * 8 + (lin >> 6);
    const int xblk = (lin >> 3) & 7;

    const int i0 = xblk * 256;
    const int b  = bh >> 4;
    const int h  = bh & 15;
    const int qrow0 = i0 + w * 64;

    // Q fragments (B-operand) for 4 row-tiles, straight from global
    bf16x8 aq[4][2];
    float  qm[4];
    #pragma unroll
    for (int rt = 0; rt < 4; ++rt) {
        const unsigned short* qrow = qs + ((size_t)bh * N_ + qrow0 + rt * 16 + l15) * 64;
        aq[rt][0] = *reinterpret_cast<const bf16x8*>(qrow + quad * 8);
        aq[rt][1] = *reinterpret_cast<const bf16x8*>(qrow + 32 + quad * 8);
        qm[rt] = maskp[b * N_ + qrow0 + rt * 16 + l15] ? 1.f : 0.f;
    }

    bf16x8 aones;
    #pragma unroll
    for (int j = 0; j < 8; ++j) aones[j] = (short)0x3F80;

    f32x4 O[4][4];     // [rt][ct2] : O^T[d-block ct2][qrow-block rt]
    f32x4 L[4];
    #pragma unroll
    for (int rt = 0; rt < 4; ++rt) {
        L[rt] = f32x4{0.f, 0.f, 0.f, 0.f};
        #pragma unroll
        for (int c = 0; c < 4; ++c) O[rt][c] = f32x4{0.f, 0.f, 0.f, 0.f};
    }

    const unsigned short* kbase = ks + (size_t)bh * N_ * 64;
    const unsigned short* vfb   = vt + (size_t)bh * 64 * N_;

    for (int kv0 = 0; kv0 < N_; kv0 += 64) {
        __syncthreads();
        // stage K rows [64][64] (b128, bank-uniform) + mask bias
        #pragma unroll
        for (int it = 0; it < 2; ++it) {
            int idx = tid + it * 256;          // 0..511
            int r = idx >> 3, g = idx & 7;
            *reinterpret_cast<uint4*>(&Ks[r][g * 8]) =
                *reinterpret_cast<const uint4*>(kbase + (size_t)(kv0 + r) * 64 + g * 8);
        }
        if (tid < 64) kb[tid] = maskp[b * N_ + kv0 + tid] ? 0.f : -1e30f;
        __syncthreads();

        // K A-fragments (shared across all 4 rt)
        bf16x8 ak[4][2];
        #pragma unroll
        for (int ct = 0; ct < 4; ++ct)
            #pragma unroll
            for (int kh = 0; kh < 2; ++kh)
                ak[ct][kh] = *reinterpret_cast<const bf16x8*>(&Ks[ct * 16 + l15][kh * 32 + quad * 8]);

        // V A-fragments DIRECT from fragment-linear vt: one 16B load each,
        // shared base + immediate offsets (ct,kh are compile-time)
        const unsigned short* vf = vfb + (size_t)(kv0 >> 6) * 4096;
        bf16x8 av[4][2];
        #pragma unroll
        for (int ct = 0; ct < 4; ++ct)
            #pragma unroll
            for (int kh = 0; kh < 2; ++kh)
                av[ct][kh] = *reinterpret_cast<const bf16x8*>(
                    vf + ((ct * 2 + kh) * 16 + l15) * 32 + quad * 8);

        f32x4 kbv[4];
        #pragma unroll
        for (int ct = 0; ct < 4; ++ct)
            kbv[ct] = *reinterpret_cast<const f32x4*>(&kb[ct * 16 + quad * 4]);

        #pragma unroll
        for (int rt = 0; rt < 4; ++rt) {
            // S^T: lane holds S[qrow=rt*16+l15][j=16ct+4q+r]; acc starts at kb[j]
            f32x4 S[4];
            #pragma unroll
            for (int ct = 0; ct < 4; ++ct) {
                S[ct] = kbv[ct];
                #pragma unroll
                for (int kh = 0; kh < 2; ++kh)
                    S[ct] = __builtin_amdgcn_mfma_f32_16x16x32_bf16(ak[ct][kh], aq[rt][kh], S[ct], 0, 0, 0);
            }
            // masked exp2 (q pre-scaled by log2e); pack directly into P B-fragments
            unsigned pk[4][2];
            #pragma unroll
            for (int ct = 0; ct < 4; ++ct) {
                float e0 = __builtin_amdgcn_exp2f(S[ct][0] * qm[rt]);
                float e1 = __builtin_amdgcn_exp2f(S[ct][1] * qm[rt]);
                float e2 = __builtin_amdgcn_exp2f(S[ct][2] * qm[rt]);
                float e3 = __builtin_amdgcn_exp2f(S[ct][3] * qm[rt]);
                pk[ct][0] = f2bf2pack(e0, e1);
                pk[ct][1] = f2bf2pack(e2, e3);
            }
            bf16x8 ap[2];
            #pragma unroll
            for (int kh = 0; kh < 2; ++kh) {
                uint4 u = uint4{pk[2 * kh][0], pk[2 * kh][1], pk[2 * kh + 1][0], pk[2 * kh + 1][1]};
                ap[kh] = __builtin_bit_cast(bf16x8, u);
            }
            // row-sums: D[m][n=qrow] = sum_k P — every lane gets its own qrow's L
            #pragma unroll
            for (int kh = 0; kh < 2; ++kh)
                L[rt] = __builtin_amdgcn_mfma_f32_16x16x32_bf16(aones, ap[kh], L[rt], 0, 0, 0);
            // O^T += V^T P^T
            #pragma unroll
            for (int ct = 0; ct < 4; ++ct)
                #pragma unroll
                for (int kh = 0; kh < 2; ++kh)
                    O[rt][ct] = __builtin_amdgcn_mfma_f32_16x16x32_bf16(av[ct][kh], ap[kh], O[rt][ct], 0, 0, 0);
        }
    }

    // epilogue: lane (q,l15) holds O^T[d=16ct+4q+r][qrow=rt*16+l15]; L[rt] components all equal
    #pragma unroll
    for (int rt = 0; rt < 4; ++rt) {
        float inv = 1.f / L[rt][0];
        float* orow = out + ((size_t)b * N_ + qrow0 + rt * 16 + l15) * HD_ + h * 64 + quad * 4;
        #pragma unroll
        for (int ct = 0; ct < 4; ++ct)
            #pragma unroll
            for (int r = 0; r < 4; ++r)
                orow[ct * 16 + r] = O[rt][ct][r] * inv;
    }
}

extern "C" void kernel_launch(void* const* d_in, const int* in_sizes, int n_in,
                              void* d_out, int out_size, void* d_ws, size_t ws_size,
                              hipStream_t stream)
{
    const float* Qv  = (const float*)d_in[0];
    const float* Kv  = (const float*)d_in[1];
    const float* Vv  = (const float*)d_in[2];
    const float* WQ  = (const float*)d_in[3];
    const float* WK  = (const float*)d_in[4];
    const float* WV  = (const float*)d_in[5];
    const int*   msk = (const int*)d_in[6];
    float* out = (float*)d_out;

    const size_t per = (size_t)B_ * H_ * N_ * 64;   // 8.4M elems, bf16
    unsigned short* qsb = (unsigned short*)d_ws;
    unsigned short* ksb = qsb + per;
    unsigned short* vtb = ksb + per;

    proj_kernel<<<dim3(N_ / 64, H_, B_ * 3), 256, 0, stream>>>(Qv, Kv, Vv, WQ, WK, WV, qsb, ksb, vtb);
    attn_kernel<<<dim3(N_ / 256, B_ * H_), 256, 0, stream>>>(qsb, ksb, vtb, msk, out);
}